// Round 10
// baseline (189.719 us; speedup 1.0000x reference)
//
#include <hip/hip_runtime.h>

// ---- problem geometry ----
#define D_MODEL 512
#define HD      1960
#define NPAD    2048          // HD padded to tile multiple
#define NVECS   720
#define MROWS   14400         // 4*3600
#define MPAD    14592         // 57*256
#define HP      66
#define WP      114
#define IMGPIX  7524          // HP*WP

typedef __bf16 bf16x8 __attribute__((ext_vector_type(8)));
typedef float  f32x4  __attribute__((ext_vector_type(4)));

__device__ __forceinline__ unsigned short f2bf(float f) {
    unsigned u = __builtin_bit_cast(unsigned, f);
    u += 0x7FFFu + ((u >> 16) & 1u);   // RNE
    return (unsigned short)(u >> 16);
}
__device__ __forceinline__ float bf2f(unsigned short s) {
    unsigned u = ((unsigned)s) << 16;
    return __builtin_bit_cast(float, u);
}

__device__ __forceinline__ void gload_lds16(const unsigned short* g, unsigned short* l) {
    __builtin_amdgcn_global_load_lds(
        (const __attribute__((address_space(1))) unsigned int*)g,
        (__attribute__((address_space(3))) unsigned int*)l,
        16, 0, 0);
}

// ---- convert x (fp32) -> bf16, zero-pad rows [14400,14592) ----
__global__ void cvt_x(const float* __restrict__ x, unsigned short* __restrict__ xb) {
    size_t i = ((size_t)blockIdx.x * 256 + threadIdx.x) * 4;
    const size_t valid = (size_t)MROWS * D_MODEL;
    if (i >= (size_t)MPAD * D_MODEL) return;
    ushort4 o;
    if (i < valid) {
        float4 v = *(const float4*)(x + i);
        o.x = f2bf(v.x); o.y = f2bf(v.y); o.z = f2bf(v.z); o.w = f2bf(v.w);
    } else {
        o.x = o.y = o.z = o.w = 0;
    }
    *(ushort4*)(xb + i) = o;
}

// ---- tiled transpose + fp32->bf16, zero-fill outside src ----
__global__ void transpose_cvt(const float* __restrict__ src, unsigned short* __restrict__ dst,
                              int srcR, int srcC, int dstR, int dstC) {
    __shared__ float tile[32][33];
    int c0 = blockIdx.x * 32;
    int r0 = blockIdx.y * 32;
    int tx = threadIdx.x, ty = threadIdx.y;   // (32,8)
    #pragma unroll
    for (int i = 0; i < 32; i += 8) {
        int sr = c0 + ty + i, sc = r0 + tx;
        tile[ty + i][tx] = (sr < srcR && sc < srcC) ? src[(size_t)sr * srcC + sc] : 0.f;
    }
    __syncthreads();
    #pragma unroll
    for (int i = 0; i < 32; i += 8) {
        int dr = r0 + ty + i, dc = c0 + tx;
        if (dr < dstR && dc < dstC)
            dst[(size_t)dr * dstC + dc] = f2bf(tile[tx][ty + i]);
    }
}

// ---- 256x256 BK=64 counted-vmcnt bf16 GEMM: C = A(MxK) * BT(NxK)^T ----
// 8 waves (2 wr x 4 wc), wave tile 128x64. LDS 128KB: [buf][A|B][half] 16KB blocks.
// LDS tile layout [128 rows][8 slots of 16B], slot = kq ^ (row&7) (conflict-free, R7-verified family).
// Staged with pre-swizzled per-lane global source + linear LDS dest.
// Pipeline: prologue stages kt0,kt1; per iter: vmcnt(8) -> barrier -> 24 ds_read + 64 MFMA
// (setprio) -> barrier -> stage kt+2. Never vmcnt(0) in-loop (T4).
// MODE 0: out bf16 TRANSPOSED hT[col*MPAD+row] + bias, skip cols >= validN (GEMM1)
// MODE 1: out fp32 partial (split-K): P[kz][row*512+col], no bias           (GEMM2)
template<int MODE>
__global__ __launch_bounds__(512, 2) void gemm256(const unsigned short* __restrict__ A,
                         const unsigned short* __restrict__ BT,
                         const float* __restrict__ bias,
                         void* __restrict__ Cout,
                         int K, int NT, int validN) {
    __shared__ unsigned short lds[65536];   // 128KB
    const int t    = threadIdx.x;
    const int lane = t & 63;
    const int wid  = t >> 6;
    const int wr   = wid >> 2, wc = wid & 3;
    const int lr   = lane & 15, lh = lane >> 4;
    const int m0   = blockIdx.y * 256, n0 = blockIdx.x * 256;
    const int kz   = (MODE == 1) ? blockIdx.z : 0;
    const unsigned short* Ab = A  + (size_t)kz * 1024;
    const unsigned short* Bb = BT + (size_t)kz * 1024;

    // staging source offsets: chunk c = i*512+t -> phys row r=c>>3, slot sp=c&7 -> logical kq=sp^(r&7)
    const int c0i = t,        r0i = c0i >> 3, q0 = (c0i & 7) ^ (r0i & 7);
    const int c1i = t + 512,  r1i = c1i >> 3, q1 = (c1i & 7) ^ (r1i & 7);
    const unsigned soffA00 = (unsigned)((m0 +       r0i) * K + q0 * 8);
    const unsigned soffA01 = (unsigned)((m0 +       r1i) * K + q1 * 8);
    const unsigned soffA10 = (unsigned)((m0 + 128 + r0i) * K + q0 * 8);
    const unsigned soffA11 = (unsigned)((m0 + 128 + r1i) * K + q1 * 8);
    const unsigned soffB00 = (unsigned)((n0 +       r0i) * K + q0 * 8);
    const unsigned soffB01 = (unsigned)((n0 +       r1i) * K + q1 * 8);
    const unsigned soffB10 = (unsigned)((n0 + 128 + r0i) * K + q0 * 8);
    const unsigned soffB11 = (unsigned)((n0 + 128 + r1i) * K + q1 * 8);

#define STAGE8(buf, kk) do { \
        unsigned short* L = lds + (buf) * 32768; \
        gload_lds16(Ab + soffA00 + (kk), L +         t * 8); \
        gload_lds16(Ab + soffA01 + (kk), L +  4096 + t * 8); \
        gload_lds16(Ab + soffA10 + (kk), L +  8192 + t * 8); \
        gload_lds16(Ab + soffA11 + (kk), L + 12288 + t * 8); \
        gload_lds16(Bb + soffB00 + (kk), L + 16384 +         t * 8); \
        gload_lds16(Bb + soffB01 + (kk), L + 16384 +  4096 + t * 8); \
        gload_lds16(Bb + soffB10 + (kk), L + 16384 +  8192 + t * 8); \
        gload_lds16(Bb + soffB11 + (kk), L + 16384 + 12288 + t * 8); \
    } while (0)

    f32x4 acc[8][4] = {};

    STAGE8(0, 0);
    if (NT > 1) STAGE8(1, 64);

    const int sl0 = lh ^ (lr & 7);        // ds_read slot, ks=0
    const int sl1 = sl0 ^ 4;              // ks=1

    for (int kt = 0; kt < NT; ++kt) {
        const int buf = kt & 1;
        if (kt + 1 < NT) { asm volatile("s_waitcnt vmcnt(8)" ::: "memory"); }
        else             { asm volatile("s_waitcnt vmcnt(0)" ::: "memory"); }
        __builtin_amdgcn_s_barrier();
        const unsigned short* La = lds + buf * 32768 + wr * 8192;
        const unsigned short* Lb = lds + buf * 32768 + 16384 + (wc >> 1) * 8192 + (wc & 1) * 4096;
        #pragma unroll
        for (int ks = 0; ks < 2; ++ks) {
            const int sl = ks ? sl1 : sl0;
            bf16x8 a[8], b[4];
            #pragma unroll
            for (int f = 0; f < 8; ++f)
                a[f] = *(const bf16x8*)(La + (f * 16 + lr) * 64 + sl * 8);
            #pragma unroll
            for (int g = 0; g < 4; ++g)
                b[g] = *(const bf16x8*)(Lb + (g * 16 + lr) * 64 + sl * 8);
            __builtin_amdgcn_s_setprio(1);
            #pragma unroll
            for (int f = 0; f < 8; ++f)
                #pragma unroll
                for (int g = 0; g < 4; ++g)
                    acc[f][g] = __builtin_amdgcn_mfma_f32_16x16x32_bf16(a[f], b[g], acc[f][g], 0, 0, 0);
            __builtin_amdgcn_s_setprio(0);
        }
        __builtin_amdgcn_s_barrier();
        if (kt + 2 < NT) STAGE8(buf, (kt + 2) * 64);
    }
#undef STAGE8

    // C/D layout: col(n)=lane&15, row(m)=(lane>>4)*4+j  [m89 verified]
    if (MODE == 0) {
        // restage full 256x256 C-tile (bias, bf16) into LDS [col][granule^swz], store hT col-major
        __syncthreads();
        #pragma unroll
        for (int f = 0; f < 8; ++f) {
            #pragma unroll
            for (int g = 0; g < 4; ++g) {
                int col = wc * 64 + g * 16 + lr;
                float bv = bias[n0 + col];
                int gr = wr * 32 + f * 4 + lh;      // row granule (rows gr*4..gr*4+3)
                ushort4 v4;
                v4.x = f2bf(acc[f][g][0] + bv);
                v4.y = f2bf(acc[f][g][1] + bv);
                v4.z = f2bf(acc[f][g][2] + bv);
                v4.w = f2bf(acc[f][g][3] + bv);
                *(ushort4*)(lds + col * 256 + ((gr ^ (col & 63)) << 2)) = v4;
            }
        }
        __syncthreads();
        unsigned short* hT = (unsigned short*)Cout;
        int col = t & 255, half = t >> 8;
        int gcol = n0 + col;
        if (gcol < validN) {
            #pragma unroll
            for (int i = 0; i < 32; ++i) {
                int gr = half * 32 + i;
                ushort4 v4 = *(const ushort4*)(lds + col * 256 + ((gr ^ (col & 63)) << 2));
                *(ushort4*)&hT[(size_t)gcol * MPAD + m0 + gr * 4] = v4;
            }
        }
    } else {
        float* P = (float*)Cout + (size_t)kz * ((size_t)MPAD * 512);
        #pragma unroll
        for (int f = 0; f < 8; ++f) {
            #pragma unroll
            for (int g = 0; g < 4; ++g) {
                int gcol = n0 + wc * 64 + g * 16 + lr;
                #pragma unroll
                for (int j = 0; j < 4; ++j) {
                    int grow = m0 + wr * 128 + f * 16 + lh * 4 + j;
                    P[(size_t)grow * 512 + gcol] = acc[f][g][j];
                }
            }
        }
    }
}

// ---- combine split-K partials + bias -> d_out (fp32) ----
__global__ void combine_k(const float* __restrict__ P, const float* __restrict__ bias,
                          float* __restrict__ out) {
    const float* P1 = P + (size_t)MPAD * 512;
    const size_t total = (size_t)MROWS * 512;
    for (size_t i = ((size_t)blockIdx.x * 256 + threadIdx.x) * 4; i < total;
         i += (size_t)gridDim.x * 256 * 4) {
        float4 a = *(const float4*)(P + i);
        float4 b = *(const float4*)(P1 + i);
        float4 bv = *(const float4*)(bias + (i & 511));
        float4 o = {a.x + b.x + bv.x, a.y + b.y + bv.y, a.z + b.z + bv.z, a.w + b.w + bv.w};
        *(float4*)(out + i) = o;
    }
}

// ---- fold + normalize + relu -> per-(b2,c) padded image (bf16) ----
// grid (HP, 200), block 128: y=blockIdx.x, blockIdx.y = b2*10+cg (4 channels/thread).
__global__ void fold_norm(const unsigned short* __restrict__ hT, unsigned short* __restrict__ img2) {
    int y  = blockIdx.x;
    int g  = blockIdx.y;
    int b2 = g / 10, cg = g % 10;
    int c0 = cg * 4;
    int x  = threadIdx.x;
    if (x >= WP) return;
    float val[4] = {0.f, 0.f, 0.f, 0.f};
    if (y >= 3 && y < 63 && x >= 3 && x < 111) {
        int kiA[3], biA[3], nki = 0;
        for (int ki = y % 3; ki < 7; ki += 3) {
            int bi = (y - ki) / 3;
            if (y - ki >= 0 && bi < 20) { kiA[nki] = ki; biA[nki] = bi; ++nki; }
        }
        int kjA[3], bjA[3], nkj = 0;
        for (int kj = x % 3; kj < 7; kj += 3) {
            int bj = (x - kj) / 3;
            if (x - kj >= 0 && bj < 36) { kjA[nkj] = kj; bjA[nkj] = bj; ++nkj; }
        }
        float s[4] = {0.f, 0.f, 0.f, 0.f};
        for (int i = 0; i < nki; ++i) {
            for (int j = 0; j < nkj; ++j) {
                int row = b2 * NVECS + biA[i] * 36 + bjA[j];
                int colb = kiA[i] * 7 + kjA[j];
                #pragma unroll
                for (int q = 0; q < 4; ++q)
                    s[q] += bf2f(hT[(size_t)((c0 + q) * 49 + colb) * MPAD + row]);
            }
        }
        float inv = 1.f / (float)(nki * nkj);
        #pragma unroll
        for (int q = 0; q < 4; ++q)
            val[q] = fmaxf(s[q] * inv, 0.f);
    }
    #pragma unroll
    for (int q = 0; q < 4; ++q)
        img2[(size_t)(b2 * 40 + c0 + q) * IMGPIX + y * WP + x] = f2bf(val[q]);
}

// ---- unfold, LDS-staged: block (b2*20+bi, cg). Stage img2 slab, write h2b coalesced. ----
__global__ void unfold_k(const unsigned short* __restrict__ img2, unsigned short* __restrict__ h2b) {
    __shared__ unsigned short lds[20 * 798];   // [cc][ki*114 + x]
    __shared__ unsigned short lut[980];        // hd_local -> cc*798 + ki*114 + kj
    const int gb = blockIdx.x;                 // b2*20 + bi
    const int cg = blockIdx.y;
    const int b2 = gb / 20, bi = gb % 20;
    const int t  = threadIdx.x;

    const unsigned short* src = img2 + (size_t)(b2 * 40 + cg * 20) * IMGPIX + (bi * 3) * WP;
    for (int p = t; p < 7980; p += 256) {
        int cc = p / 399, rem2 = p - cc * 399;
        *(ushort2*)&lds[cc * 798 + rem2 * 2] =
            *(const ushort2*)&src[(size_t)cc * IMGPIX + rem2 * 2];
    }
    for (int L = t; L < 980; L += 256) {
        int cc = L / 49, kk = L - cc * 49;
        lut[L] = (unsigned short)(cc * 798 + (kk / 7) * 114 + (kk % 7));
    }
    __syncthreads();

    const int cpr   = (cg == 0) ? 245 : 267;
    const int total = 36 * cpr;
    const int rowbase = b2 * NVECS + bi * 36;
    const int hdbase  = cg * 980;
    for (int i = t; i < total; i += 256) {
        int r = i / cpr, q = i - r * cpr;
        int hl = q * 4;
        ushort4 v;
        unsigned short* vv = (unsigned short*)&v;
        #pragma unroll
        for (int e = 0; e < 4; ++e) {
            int h = hl + e;
            vv[e] = (h < 980) ? lds[lut[h] + r * 3] : (unsigned short)0;
        }
        *(ushort4*)&h2b[(size_t)(rowbase + r) * NPAD + hdbase + hl] = v;
    }
}

extern "C" void kernel_launch(void* const* d_in, const int* in_sizes, int n_in,
                              void* d_out, int out_size, void* d_ws, size_t ws_size,
                              hipStream_t stream) {
    const float* x  = (const float*)d_in[0];
    const float* W1 = (const float*)d_in[1];
    const float* b1 = (const float*)d_in[2];
    const float* W2 = (const float*)d_in[3];
    const float* b2 = (const float*)d_in[4];
    float* out = (float*)d_out;

    // workspace (bf16 elems): xb | W1T | W2T | hT (reused as split-K fp32 partials) | h2b | img2
    unsigned short* xb   = (unsigned short*)d_ws;                 // MPAD*512
    unsigned short* W1T  = xb   + (size_t)MPAD * D_MODEL;         // 2048*512
    unsigned short* W2T  = W1T  + (size_t)NPAD * D_MODEL;         // 512*2048
    unsigned short* hT   = W2T  + (size_t)D_MODEL * NPAD;         // NPAD*MPAD bf16 == 2x MPAD*512 fp32
    unsigned short* h2b  = hT   + (size_t)NPAD * MPAD;            // MPAD*NPAD
    unsigned short* img2 = h2b  + (size_t)MPAD * NPAD;            // 800*7524

    cvt_x<<<(MPAD * D_MODEL / 4 + 255) / 256, 256, 0, stream>>>(x, xb);

    dim3 tb(32, 8);
    transpose_cvt<<<dim3(512 / 32, NPAD / 32), tb, 0, stream>>>(W1, W1T, D_MODEL, HD, NPAD, D_MODEL);
    transpose_cvt<<<dim3(NPAD / 32, 512 / 32), tb, 0, stream>>>(W2, W2T, HD, D_MODEL, D_MODEL, NPAD);

    // GEMM1: hT = (xb @ W1T^T + b1)^T  (bf16 transposed out), 256^2 counted-vmcnt
    gemm256<0><<<dim3(NPAD / 256, MPAD / 256), 512, 0, stream>>>(
        xb, W1T, b1, hT, D_MODEL, D_MODEL / 64, HD);

    fold_norm<<<dim3(HP, 200), 128, 0, stream>>>(hT, img2);
    unfold_k<<<dim3(400, 2), 256, 0, stream>>>(img2, h2b);

    // GEMM2 split-K=2: partials into hT buffer (fp32), then combine + bias
    gemm256<1><<<dim3(D_MODEL / 256, MPAD / 256, 2), 512, 0, stream>>>(
        h2b, W2T, b2, hT, NPAD, 1024 / 64, D_MODEL);
    combine_k<<<2048, 256, 0, stream>>>((const float*)hT, b2, out);
}

// Round 11
// 187.499 us; speedup vs baseline: 1.0118x; 1.0118x over previous
//
#include <hip/hip_runtime.h>

// ---- problem geometry ----
#define D_MODEL 512
#define HD      1960
#define NPAD    2048          // HD padded to tile multiple
#define NVECS   720
#define MROWS   14400         // 4*3600
#define MPAD    14592         // 114*128
#define HP      66
#define WP      114
#define IMGPIX  7524          // HP*WP

typedef __bf16 bf16x8 __attribute__((ext_vector_type(8)));
typedef float  f32x4  __attribute__((ext_vector_type(4)));

__device__ __forceinline__ unsigned short f2bf(float f) {
    unsigned u = __builtin_bit_cast(unsigned, f);
    u += 0x7FFFu + ((u >> 16) & 1u);   // RNE
    return (unsigned short)(u >> 16);
}
__device__ __forceinline__ float bf2f(unsigned short s) {
    unsigned u = ((unsigned)s) << 16;
    return __builtin_bit_cast(float, u);
}

__device__ __forceinline__ void gload_lds16(const unsigned short* g, unsigned short* l) {
    __builtin_amdgcn_global_load_lds(
        (const __attribute__((address_space(1))) unsigned int*)g,
        (__attribute__((address_space(3))) unsigned int*)l,
        16, 0, 0);
}

// ---- convert x (fp32) -> bf16, zero-pad rows [14400,14592) ----
__global__ void cvt_x(const float* __restrict__ x, unsigned short* __restrict__ xb) {
    size_t i = ((size_t)blockIdx.x * 256 + threadIdx.x) * 4;
    const size_t valid = (size_t)MROWS * D_MODEL;
    if (i >= (size_t)MPAD * D_MODEL) return;
    ushort4 o;
    if (i < valid) {
        float4 v = *(const float4*)(x + i);
        o.x = f2bf(v.x); o.y = f2bf(v.y); o.z = f2bf(v.z); o.w = f2bf(v.w);
    } else {
        o.x = o.y = o.z = o.w = 0;
    }
    *(ushort4*)(xb + i) = o;
}

// ---- tiled transpose + fp32->bf16, zero-fill outside src ----
__global__ void transpose_cvt(const float* __restrict__ src, unsigned short* __restrict__ dst,
                              int srcR, int srcC, int dstR, int dstC) {
    __shared__ float tile[32][33];
    int c0 = blockIdx.x * 32;
    int r0 = blockIdx.y * 32;
    int tx = threadIdx.x, ty = threadIdx.y;   // (32,8)
    #pragma unroll
    for (int i = 0; i < 32; i += 8) {
        int sr = c0 + ty + i, sc = r0 + tx;
        tile[ty + i][tx] = (sr < srcR && sc < srcC) ? src[(size_t)sr * srcC + sc] : 0.f;
    }
    __syncthreads();
    #pragma unroll
    for (int i = 0; i < 32; i += 8) {
        int dr = r0 + ty + i, dc = c0 + tx;
        if (dr < dstR && dc < dstC)
            dst[(size_t)dr * dstC + dc] = f2bf(tile[tx][ty + i]);
    }
}

// ---- m97-style bf16 GEMM, 128^2 tile, XCD-chunked blockIdx swizzle (T1) ----
// C = A(MxK) * BT(NxK)^T (+bias)
// MODE 0: out bf16 TRANSPOSED  hT[col*MPAD + row], skip cols >= validN (GEMM1)
// MODE 1: out fp32 row-major (ldc=512), skip rows >= validM           (GEMM2)
template<int MODE>
__global__ void gemm_bt(const unsigned short* __restrict__ A,
                        const unsigned short* __restrict__ BT,
                        const float* __restrict__ bias,
                        void* __restrict__ Cout,
                        int K, int ldc, int validN, int validM) {
    __shared__ unsigned short smem[128 * 128];   // 32 KB: As|Bs during K-loop, C-tile in epilogue
    unsigned short* As = smem;
    unsigned short* Bs = smem + 128 * 64;
    const int t    = threadIdx.x;
    const int wid  = t >> 6, lane = t & 63;
    const int wr   = wid >> 1, wc = wid & 1;
    const int lr   = lane & 15, lh = lane >> 4;

    // XCD-chunked swizzle: XCD k (wgid%8 round-robin) gets a contiguous tile chunk
    // -> blocks sharing an A-panel (same m-row) land on the same XCD's L2.
    const int nwg = gridDim.x * gridDim.y;       // divisible by 8 (1824 / 456)
    const int bid = blockIdx.x + blockIdx.y * gridDim.x;
    const int cpx = nwg >> 3;
    const int swz = (bid & 7) * cpx + (bid >> 3);
    const int m0  = (swz / gridDim.x) * 128, n0 = (swz % gridDim.x) * 128;

    f32x4 acc[4][4] = {};

    const unsigned short* Aptr = A  + (size_t)(m0 + (t >> 3)) * K + (t & 7) * 8;
    const unsigned short* Bptr = BT + (size_t)(n0 + (t >> 3)) * K + (t & 7) * 8;
    unsigned short* Asl = As + t * 8;
    unsigned short* Bsl = Bs + t * 8;

    for (int kt = 0; kt < K; kt += 64) {
        #pragma unroll
        for (int i = 0; i < 4; ++i) {
            gload_lds16(Aptr + (size_t)(i * 32) * K + kt, Asl + i * 2048);
            gload_lds16(Bptr + (size_t)(i * 32) * K + kt, Bsl + i * 2048);
        }
        __syncthreads();
        #pragma unroll
        for (int ks = 0; ks < 2; ++ks) {
            bf16x8 a[4], b[4];
            #pragma unroll
            for (int f = 0; f < 4; ++f) {
                a[f] = *(const bf16x8*)&As[(wr * 64 + f * 16 + lr) * 64 + ks * 32 + lh * 8];
                b[f] = *(const bf16x8*)&Bs[(wc * 64 + f * 16 + lr) * 64 + ks * 32 + lh * 8];
            }
            #pragma unroll
            for (int fm = 0; fm < 4; ++fm)
                #pragma unroll
                for (int fn = 0; fn < 4; ++fn)
                    acc[fm][fn] = __builtin_amdgcn_mfma_f32_16x16x32_bf16(
                        a[fm], b[fn], acc[fm][fn], 0, 0, 0);
        }
        __syncthreads();
    }

    // C/D layout: col=lane&15, row=(lane>>4)*4+j  [m89 verified]
    if (MODE == 0) {
        // stage C-tile (bias applied, bf16) into swizzled LDS, then write hT col-major coalesced
        #pragma unroll
        for (int fm = 0; fm < 4; ++fm) {
            #pragma unroll
            for (int fn = 0; fn < 4; ++fn) {
                int lcol = wc * 64 + fn * 16 + lr;
                float bv = bias[n0 + lcol];
                #pragma unroll
                for (int j = 0; j < 4; ++j) {
                    int lrow = wr * 64 + fm * 16 + lh * 4 + j;
                    smem[lcol * 128 + (lrow ^ ((lcol & 15) << 3))] =
                        f2bf(acc[fm][fn][j] + bv);
                }
            }
        }
        __syncthreads();
        unsigned short* hT = (unsigned short*)Cout;
        int col = t >> 1, half = t & 1;
        int gcol = n0 + col;
        if (gcol < validN) {
            #pragma unroll
            for (int r = 0; r < 16; ++r) {
                int row = half * 64 + r * 4;
                ushort4 v4 = *(const ushort4*)&smem[col * 128 + (row ^ ((col & 15) << 3))];
                *(ushort4*)&hT[(size_t)gcol * MPAD + m0 + row] = v4;
            }
        }
    } else {
        #pragma unroll
        for (int fm = 0; fm < 4; ++fm) {
            #pragma unroll
            for (int fn = 0; fn < 4; ++fn) {
                int gcol = n0 + wc * 64 + fn * 16 + lr;
                float bv = bias[gcol];
                #pragma unroll
                for (int j = 0; j < 4; ++j) {
                    int grow = m0 + wr * 64 + fm * 16 + lh * 4 + j;
                    if (grow < validM)
                        ((float*)Cout)[(size_t)grow * ldc + gcol] = acc[fm][fn][j] + bv;
                }
            }
        }
    }
}

// ---- fold + normalize + relu -> per-(b2,c) padded image (bf16) ----
// grid (HP, 200), block 128: y=blockIdx.x, blockIdx.y = b2*10+cg (4 channels/thread).
__global__ void fold_norm(const unsigned short* __restrict__ hT, unsigned short* __restrict__ img2) {
    int y  = blockIdx.x;
    int g  = blockIdx.y;
    int b2 = g / 10, cg = g % 10;
    int c0 = cg * 4;
    int x  = threadIdx.x;
    if (x >= WP) return;
    float val[4] = {0.f, 0.f, 0.f, 0.f};
    if (y >= 3 && y < 63 && x >= 3 && x < 111) {
        int kiA[3], biA[3], nki = 0;
        for (int ki = y % 3; ki < 7; ki += 3) {
            int bi = (y - ki) / 3;
            if (y - ki >= 0 && bi < 20) { kiA[nki] = ki; biA[nki] = bi; ++nki; }
        }
        int kjA[3], bjA[3], nkj = 0;
        for (int kj = x % 3; kj < 7; kj += 3) {
            int bj = (x - kj) / 3;
            if (x - kj >= 0 && bj < 36) { kjA[nkj] = kj; bjA[nkj] = bj; ++nkj; }
        }
        float s[4] = {0.f, 0.f, 0.f, 0.f};
        for (int i = 0; i < nki; ++i) {
            for (int j = 0; j < nkj; ++j) {
                int row = b2 * NVECS + biA[i] * 36 + bjA[j];
                int colb = kiA[i] * 7 + kjA[j];
                #pragma unroll
                for (int q = 0; q < 4; ++q)
                    s[q] += bf2f(hT[(size_t)((c0 + q) * 49 + colb) * MPAD + row]);
            }
        }
        float inv = 1.f / (float)(nki * nkj);
        #pragma unroll
        for (int q = 0; q < 4; ++q)
            val[q] = fmaxf(s[q] * inv, 0.f);
    }
    #pragma unroll
    for (int q = 0; q < 4; ++q)
        img2[(size_t)(b2 * 40 + c0 + q) * IMGPIX + y * WP + x] = f2bf(val[q]);
}

// ---- unfold, LDS-staged: block (b2*20+bi, cg). Stage img2 slab, write h2b coalesced. ----
// h2b pad rows [14400,14592) left unwritten: they only feed GEMM2 output rows >= validM (never stored).
__global__ void unfold_k(const unsigned short* __restrict__ img2, unsigned short* __restrict__ h2b) {
    __shared__ unsigned short lds[20 * 798];   // [cc][ki*114 + x]
    __shared__ unsigned short lut[980];        // hd_local -> cc*798 + ki*114 + kj
    const int gb = blockIdx.x;                 // b2*20 + bi
    const int cg = blockIdx.y;
    const int b2 = gb / 20, bi = gb % 20;
    const int t  = threadIdx.x;

    const unsigned short* src = img2 + (size_t)(b2 * 40 + cg * 20) * IMGPIX + (bi * 3) * WP;
    for (int p = t; p < 7980; p += 256) {
        int cc = p / 399, rem2 = p - cc * 399;
        *(ushort2*)&lds[cc * 798 + rem2 * 2] =
            *(const ushort2*)&src[(size_t)cc * IMGPIX + rem2 * 2];
    }
    for (int L = t; L < 980; L += 256) {
        int cc = L / 49, kk = L - cc * 49;
        lut[L] = (unsigned short)(cc * 798 + (kk / 7) * 114 + (kk % 7));
    }
    __syncthreads();

    const int cpr   = (cg == 0) ? 245 : 267;
    const int total = 36 * cpr;
    const int rowbase = b2 * NVECS + bi * 36;
    const int hdbase  = cg * 980;
    for (int i = t; i < total; i += 256) {
        int r = i / cpr, q = i - r * cpr;
        int hl = q * 4;
        ushort4 v;
        unsigned short* vv = (unsigned short*)&v;
        #pragma unroll
        for (int e = 0; e < 4; ++e) {
            int h = hl + e;
            vv[e] = (h < 980) ? lds[lut[h] + r * 3] : (unsigned short)0;
        }
        *(ushort4*)&h2b[(size_t)(rowbase + r) * NPAD + hdbase + hl] = v;
    }
}

extern "C" void kernel_launch(void* const* d_in, const int* in_sizes, int n_in,
                              void* d_out, int out_size, void* d_ws, size_t ws_size,
                              hipStream_t stream) {
    const float* x  = (const float*)d_in[0];
    const float* W1 = (const float*)d_in[1];
    const float* b1 = (const float*)d_in[2];
    const float* W2 = (const float*)d_in[3];
    const float* b2 = (const float*)d_in[4];
    float* out = (float*)d_out;

    // workspace (bf16 elems): xb | W1T | W2T | hT | h2b | img2
    unsigned short* xb   = (unsigned short*)d_ws;                 // MPAD*512
    unsigned short* W1T  = xb   + (size_t)MPAD * D_MODEL;         // 2048*512
    unsigned short* W2T  = W1T  + (size_t)NPAD * D_MODEL;         // 512*2048
    unsigned short* hT   = W2T  + (size_t)D_MODEL * NPAD;         // NPAD*MPAD (transposed)
    unsigned short* h2b  = hT   + (size_t)NPAD * MPAD;            // MPAD*NPAD
    unsigned short* img2 = h2b  + (size_t)MPAD * NPAD;            // 800*7524

    cvt_x<<<(MPAD * D_MODEL / 4 + 255) / 256, 256, 0, stream>>>(x, xb);

    dim3 tb(32, 8);
    transpose_cvt<<<dim3(512 / 32, NPAD / 32), tb, 0, stream>>>(W1, W1T, D_MODEL, HD, NPAD, D_MODEL);
    transpose_cvt<<<dim3(NPAD / 32, 512 / 32), tb, 0, stream>>>(W2, W2T, HD, D_MODEL, D_MODEL, NPAD);

    // GEMM1: hT = (xb @ W1T^T + b1)^T   (bf16, transposed out), grid 16x114 = 1824 (8|1824)
    gemm_bt<0><<<dim3(NPAD / 128, MPAD / 128), 256, 0, stream>>>(
        xb, W1T, b1, hT, D_MODEL, 0, HD, MPAD);

    fold_norm<<<dim3(HP, 200), 128, 0, stream>>>(hT, img2);
    unfold_k<<<dim3(400, 2), 256, 0, stream>>>(img2, h2b);

    // GEMM2: out = h2b @ W2T^T + b2  (fp32, rows<14400 only), grid 4x114 = 456 (8|456)
    gemm_bt<1><<<dim3(512 / 128, MPAD / 128), 256, 0, stream>>>(
        h2b, W2T, b2, out, NPAD, D_MODEL, D_MODEL, MROWS);
}

// Round 12
// 177.868 us; speedup vs baseline: 1.0666x; 1.0541x over previous
//
#include <hip/hip_runtime.h>

// ---- problem geometry ----
#define D_MODEL 512
#define HD      1960
#define NPAD    2048          // HD padded to tile multiple
#define NVECS   720
#define MROWS   14400         // 4*3600
#define MPAD    14464         // 113*128
#define HP      66
#define WP      114
#define IMGPIX  7524          // HP*WP

typedef __bf16 bf16x8 __attribute__((ext_vector_type(8)));
typedef float  f32x4  __attribute__((ext_vector_type(4)));

__device__ __forceinline__ unsigned short f2bf(float f) {
    unsigned u = __builtin_bit_cast(unsigned, f);
    u += 0x7FFFu + ((u >> 16) & 1u);   // RNE
    return (unsigned short)(u >> 16);
}
__device__ __forceinline__ float bf2f(unsigned short s) {
    unsigned u = ((unsigned)s) << 16;
    return __builtin_bit_cast(float, u);
}

__device__ __forceinline__ void gload_lds16(const unsigned short* g, unsigned short* l) {
    __builtin_amdgcn_global_load_lds(
        (const __attribute__((address_space(1))) unsigned int*)g,
        (__attribute__((address_space(3))) unsigned int*)l,
        16, 0, 0);
}

// ---- convert x (fp32) -> bf16, zero-pad rows [14400,14464) ----
__global__ void cvt_x(const float* __restrict__ x, unsigned short* __restrict__ xb) {
    size_t i = ((size_t)blockIdx.x * 256 + threadIdx.x) * 4;
    const size_t valid = (size_t)MROWS * D_MODEL;
    if (i >= (size_t)MPAD * D_MODEL) return;
    ushort4 o;
    if (i < valid) {
        float4 v = *(const float4*)(x + i);
        o.x = f2bf(v.x); o.y = f2bf(v.y); o.z = f2bf(v.z); o.w = f2bf(v.w);
    } else {
        o.x = o.y = o.z = o.w = 0;
    }
    *(ushort4*)(xb + i) = o;
}

// ---- tiled transpose + fp32->bf16, zero-fill outside src ----
__global__ void transpose_cvt(const float* __restrict__ src, unsigned short* __restrict__ dst,
                              int srcR, int srcC, int dstR, int dstC) {
    __shared__ float tile[32][33];
    int c0 = blockIdx.x * 32;
    int r0 = blockIdx.y * 32;
    int tx = threadIdx.x, ty = threadIdx.y;   // (32,8)
    #pragma unroll
    for (int i = 0; i < 32; i += 8) {
        int sr = c0 + ty + i, sc = r0 + tx;
        tile[ty + i][tx] = (sr < srcR && sc < srcC) ? src[(size_t)sr * srcC + sc] : 0.f;
    }
    __syncthreads();
    #pragma unroll
    for (int i = 0; i < 32; i += 8) {
        int dr = r0 + ty + i, dc = c0 + tx;
        if (dr < dstR && dc < dstC)
            dst[(size_t)dr * dstC + dc] = f2bf(tile[tx][ty + i]);
    }
}

// ---- 128x128 BK=64 double-buffered counted-vmcnt bf16 GEMM ----
// C = A(MxK) * BT(NxK)^T (+bias). 4 waves (2x2), wave tile 64x64.
// LDS 64KB = 2 bufs x [A 128x64 | B 128x64] with slot-XOR layout (R10-proven, 0 conflicts):
//   tile = [128 phys rows][8 slots of 8 ushorts]; phys slot sp at row r holds logical
//   k-quad kq = sp ^ (r&7). Staged via pre-swizzled global source + linear LDS dest.
// Pipeline (T4): per tile t: issue STAGE(t+1) -> vmcnt(8) (tile t landed, t+1 in flight,
// never 0 in-loop) -> barrier -> 16 ds_read + 32 MFMA (setprio) -> barrier.
// MODE 0: out bf16 TRANSPOSED  hT[col*MPAD + row], skip cols >= validN (GEMM1)
// MODE 1: out fp32 row-major (ldc=512), skip rows >= validM           (GEMM2)
template<int MODE>
__global__ __launch_bounds__(256) void gemm_bt(const unsigned short* __restrict__ A,
                        const unsigned short* __restrict__ BT,
                        const float* __restrict__ bias,
                        void* __restrict__ Cout,
                        int K, int ldc, int validN, int validM) {
    __shared__ unsigned short lds[2][16384];   // 64KB total
    const int t    = threadIdx.x;
    const int wid  = t >> 6, lane = t & 63;
    const int wr   = wid >> 1, wc = wid & 1;
    const int lr   = lane & 15, lh = lane >> 4;
    const int m0   = blockIdx.y * 128, n0 = blockIdx.x * 128;

    // staging chunk map: chunk c in [0,1024) per matrix tile; this thread owns c = t + i*256
    int rr[4], qq[4];
    #pragma unroll
    for (int i = 0; i < 4; ++i) {
        int c = t + i * 256;
        rr[i] = c >> 3;
        qq[i] = (c & 7) ^ (rr[i] & 7);
    }

#define STAGE(buf, kt) do { \
        unsigned short* LA = &lds[buf][0]; \
        unsigned short* LB = &lds[buf][8192]; \
        _Pragma("unroll") \
        for (int i = 0; i < 4; ++i) { \
            gload_lds16(A  + (size_t)(m0 + rr[i]) * K + (kt) + qq[i] * 8, LA + (t + i * 256) * 8); \
            gload_lds16(BT + (size_t)(n0 + rr[i]) * K + (kt) + qq[i] * 8, LB + (t + i * 256) * 8); \
        } \
    } while (0)

    f32x4 acc[4][4] = {};
    const int NT = K >> 6;

    STAGE(0, 0);
    for (int tt = 0; tt < NT; ++tt) {
        if (tt + 1 < NT) {
            STAGE((tt + 1) & 1, (tt + 1) * 64);
            asm volatile("s_waitcnt vmcnt(8)" ::: "memory");
        } else {
            asm volatile("s_waitcnt vmcnt(0)" ::: "memory");
        }
        __builtin_amdgcn_s_barrier();
        __builtin_amdgcn_sched_barrier(0);
        const unsigned short* La = &lds[tt & 1][0];
        const unsigned short* Lb = &lds[tt & 1][8192];
        #pragma unroll
        for (int ks = 0; ks < 2; ++ks) {
            bf16x8 a[4], b[4];
            #pragma unroll
            for (int f = 0; f < 4; ++f) {
                int row = wr * 64 + f * 16 + lr;
                int sl  = (ks * 4 + lh) ^ (lr & 7);
                a[f] = *(const bf16x8*)(La + row * 64 + sl * 8);
            }
            #pragma unroll
            for (int g = 0; g < 4; ++g) {
                int row = wc * 64 + g * 16 + lr;
                int sl  = (ks * 4 + lh) ^ (lr & 7);
                b[g] = *(const bf16x8*)(Lb + row * 64 + sl * 8);
            }
            __builtin_amdgcn_s_setprio(1);
            #pragma unroll
            for (int fm = 0; fm < 4; ++fm)
                #pragma unroll
                for (int fn = 0; fn < 4; ++fn)
                    acc[fm][fn] = __builtin_amdgcn_mfma_f32_16x16x32_bf16(
                        a[fm], b[fn], acc[fm][fn], 0, 0, 0);
            __builtin_amdgcn_s_setprio(0);
        }
        __builtin_amdgcn_s_barrier();
        __builtin_amdgcn_sched_barrier(0);
    }
#undef STAGE

    // C/D layout: col=lane&15, row=(lane>>4)*4+j  [m89 verified]
    if (MODE == 0) {
        // stage C-tile (bias applied, bf16) into swizzled LDS, then write hT col-major coalesced
        unsigned short* smem = &lds[0][0];   // 16384 ushorts
        #pragma unroll
        for (int fm = 0; fm < 4; ++fm) {
            #pragma unroll
            for (int fn = 0; fn < 4; ++fn) {
                int lcol = wc * 64 + fn * 16 + lr;
                float bv = bias[n0 + lcol];
                #pragma unroll
                for (int j = 0; j < 4; ++j) {
                    int lrow = wr * 64 + fm * 16 + lh * 4 + j;
                    smem[lcol * 128 + (lrow ^ ((lcol & 15) << 3))] =
                        f2bf(acc[fm][fn][j] + bv);
                }
            }
        }
        __syncthreads();
        unsigned short* hT = (unsigned short*)Cout;
        int col = t >> 1, half = t & 1;
        int gcol = n0 + col;
        if (gcol < validN) {
            #pragma unroll
            for (int r = 0; r < 16; ++r) {
                int row = half * 64 + r * 4;
                ushort4 v4 = *(const ushort4*)&smem[col * 128 + (row ^ ((col & 15) << 3))];
                *(ushort4*)&hT[(size_t)gcol * MPAD + m0 + row] = v4;
            }
        }
    } else {
        #pragma unroll
        for (int fm = 0; fm < 4; ++fm) {
            #pragma unroll
            for (int fn = 0; fn < 4; ++fn) {
                int gcol = n0 + wc * 64 + fn * 16 + lr;
                float bv = bias[gcol];
                #pragma unroll
                for (int j = 0; j < 4; ++j) {
                    int grow = m0 + wr * 64 + fm * 16 + lh * 4 + j;
                    if (grow < validM)
                        ((float*)Cout)[(size_t)grow * ldc + gcol] = acc[fm][fn][j] + bv;
                }
            }
        }
    }
}

// ---- fold + normalize + relu -> per-(b2,c) padded image (bf16) ----
// grid (HP, 200), block 128: y=blockIdx.x, blockIdx.y = b2*10+cg (4 channels/thread).
__global__ void fold_norm(const unsigned short* __restrict__ hT, unsigned short* __restrict__ img2) {
    int y  = blockIdx.x;
    int g  = blockIdx.y;
    int b2 = g / 10, cg = g % 10;
    int c0 = cg * 4;
    int x  = threadIdx.x;
    if (x >= WP) return;
    float val[4] = {0.f, 0.f, 0.f, 0.f};
    if (y >= 3 && y < 63 && x >= 3 && x < 111) {
        int kiA[3], biA[3], nki = 0;
        for (int ki = y % 3; ki < 7; ki += 3) {
            int bi = (y - ki) / 3;
            if (y - ki >= 0 && bi < 20) { kiA[nki] = ki; biA[nki] = bi; ++nki; }
        }
        int kjA[3], bjA[3], nkj = 0;
        for (int kj = x % 3; kj < 7; kj += 3) {
            int bj = (x - kj) / 3;
            if (x - kj >= 0 && bj < 36) { kjA[nkj] = kj; bjA[nkj] = bj; ++nkj; }
        }
        float s[4] = {0.f, 0.f, 0.f, 0.f};
        for (int i = 0; i < nki; ++i) {
            for (int j = 0; j < nkj; ++j) {
                int row = b2 * NVECS + biA[i] * 36 + bjA[j];
                int colb = kiA[i] * 7 + kjA[j];
                #pragma unroll
                for (int q = 0; q < 4; ++q)
                    s[q] += bf2f(hT[(size_t)((c0 + q) * 49 + colb) * MPAD + row]);
            }
        }
        float inv = 1.f / (float)(nki * nkj);
        #pragma unroll
        for (int q = 0; q < 4; ++q)
            val[q] = fmaxf(s[q] * inv, 0.f);
    }
    #pragma unroll
    for (int q = 0; q < 4; ++q)
        img2[(size_t)(b2 * 40 + c0 + q) * IMGPIX + y * WP + x] = f2bf(val[q]);
}

// ---- unfold, LDS-staged: block (b2*20+bi, cg). Stage img2 slab, write h2b coalesced. ----
// h2b pad rows [14400,14464) left unwritten: they only feed GEMM2 output rows >= validM (never stored).
__global__ void unfold_k(const unsigned short* __restrict__ img2, unsigned short* __restrict__ h2b) {
    __shared__ unsigned short lds[20 * 798];   // [cc][ki*114 + x]
    __shared__ unsigned short lut[980];        // hd_local -> cc*798 + ki*114 + kj
    const int gb = blockIdx.x;                 // b2*20 + bi
    const int cg = blockIdx.y;
    const int b2 = gb / 20, bi = gb % 20;
    const int t  = threadIdx.x;

    const unsigned short* src = img2 + (size_t)(b2 * 40 + cg * 20) * IMGPIX + (bi * 3) * WP;
    for (int p = t; p < 7980; p += 256) {
        int cc = p / 399, rem2 = p - cc * 399;
        *(ushort2*)&lds[cc * 798 + rem2 * 2] =
            *(const ushort2*)&src[(size_t)cc * IMGPIX + rem2 * 2];
    }
    for (int L = t; L < 980; L += 256) {
        int cc = L / 49, kk = L - cc * 49;
        lut[L] = (unsigned short)(cc * 798 + (kk / 7) * 114 + (kk % 7));
    }
    __syncthreads();

    const int cpr   = (cg == 0) ? 245 : 267;
    const int total = 36 * cpr;
    const int rowbase = b2 * NVECS + bi * 36;
    const int hdbase  = cg * 980;
    for (int i = t; i < total; i += 256) {
        int r = i / cpr, q = i - r * cpr;
        int hl = q * 4;
        ushort4 v;
        unsigned short* vv = (unsigned short*)&v;
        #pragma unroll
        for (int e = 0; e < 4; ++e) {
            int h = hl + e;
            vv[e] = (h < 980) ? lds[lut[h] + r * 3] : (unsigned short)0;
        }
        *(ushort4*)&h2b[(size_t)(rowbase + r) * NPAD + hdbase + hl] = v;
    }
}

extern "C" void kernel_launch(void* const* d_in, const int* in_sizes, int n_in,
                              void* d_out, int out_size, void* d_ws, size_t ws_size,
                              hipStream_t stream) {
    const float* x  = (const float*)d_in[0];
    const float* W1 = (const float*)d_in[1];
    const float* b1 = (const float*)d_in[2];
    const float* W2 = (const float*)d_in[3];
    const float* b2 = (const float*)d_in[4];
    float* out = (float*)d_out;

    // workspace (bf16 elems): xb | W1T | W2T | hT | h2b | img2
    unsigned short* xb   = (unsigned short*)d_ws;                 // MPAD*512
    unsigned short* W1T  = xb   + (size_t)MPAD * D_MODEL;         // 2048*512
    unsigned short* W2T  = W1T  + (size_t)NPAD * D_MODEL;         // 512*2048
    unsigned short* hT   = W2T  + (size_t)D_MODEL * NPAD;         // NPAD*MPAD (transposed)
    unsigned short* h2b  = hT   + (size_t)NPAD * MPAD;            // MPAD*NPAD
    unsigned short* img2 = h2b  + (size_t)MPAD * NPAD;            // 800*7524

    cvt_x<<<(MPAD * D_MODEL / 4 + 255) / 256, 256, 0, stream>>>(x, xb);

    dim3 tb(32, 8);
    transpose_cvt<<<dim3(512 / 32, NPAD / 32), tb, 0, stream>>>(W1, W1T, D_MODEL, HD, NPAD, D_MODEL);
    transpose_cvt<<<dim3(NPAD / 32, 512 / 32), tb, 0, stream>>>(W2, W2T, HD, D_MODEL, D_MODEL, NPAD);

    // GEMM1: hT = (xb @ W1T^T + b1)^T   (bf16, transposed out), grid 16x113
    gemm_bt<0><<<dim3(NPAD / 128, MPAD / 128), 256, 0, stream>>>(
        xb, W1T, b1, hT, D_MODEL, 0, HD, MPAD);

    fold_norm<<<dim3(HP, 200), 128, 0, stream>>>(hT, img2);
    unfold_k<<<dim3(400, 2), 256, 0, stream>>>(img2, h2b);

    // GEMM2: out = h2b @ W2T^T + b2  (fp32, rows<14400 only), grid 4x113
    gemm_bt<1><<<dim3(512 / 128, MPAD / 128), 256, 0, stream>>>(
        h2b, W2T, b2, out, NPAD, D_MODEL, D_MODEL, MROWS);
}